// Round 1
// baseline (2642.245 us; speedup 1.0000x reference)
//
#include <hip/hip_runtime.h>
#include <hip/hip_bf16.h>
#include <math.h>

// ---------- problem constants ----------
// x (2,3,512,512); grid 64x64 tokens of 768 ch; 8 windows of 32x32=1024 tokens
// heads=8, HD=96, F=16, rope feat dim 64, ||feat||^2 = 32 exactly.

// ---------------- bilinear 2x resize (clamp-to-edge == jax renormalized) ----------------
__global__ __launch_bounds__(256) void k_resize(const float* __restrict__ x, float* __restrict__ rx)
{
    int idx = blockIdx.x * 256 + threadIdx.x;           // < 6291456 exactly
    int X = idx & 1023;
    int Y = (idx >> 10) & 1023;
    int bc = idx >> 20;                                 // 0..5 (b*3+c)
    float sy = Y * 0.5f - 0.25f;
    float sx = X * 0.5f - 0.25f;
    int y0 = (int)floorf(sy), x0 = (int)floorf(sx);
    float fy = sy - (float)y0, fx = sx - (float)x0;
    int y1 = y0 + 1, x1 = x0 + 1;
    y0 = max(0, min(511, y0)); y1 = max(0, min(511, y1));
    x0 = max(0, min(511, x0)); x1 = max(0, min(511, x1));
    const float* p = x + (size_t)bc * (512 * 512);
    float v00 = p[y0 * 512 + x0], v01 = p[y0 * 512 + x1];
    float v10 = p[y1 * 512 + x0], v11 = p[y1 * 512 + x1];
    rx[idx] = (1.f - fy) * ((1.f - fx) * v00 + fx * v01) + fy * ((1.f - fx) * v10 + fx * v11);
}

// ---------------- rope relative table R[dy+31][dx+31] ----------------
__global__ void k_rsmall(float* __restrict__ rs)
{
    int e = blockIdx.x * 256 + threadIdx.x;
    if (e >= 63 * 63) return;
    float dy = (float)(e / 63 - 31);
    float dx = (float)(e % 63 - 31);
    float s = 0.f;
    for (int f = 0; f < 16; f++) {
        float invf = powf(10.0f, -(float)f / 16.0f);
        s += cosf(dx * invf) + cosf(dy * invf);
    }
    rs[e] = s;
}

// ---------------- origin conv (8x8 s8, groups=3) + LayerNorm, window-ordered out ----------------
__global__ __launch_bounds__(256) void k_conv_origin_ln(
    const float* __restrict__ x, const float* __restrict__ wgt,
    const float* __restrict__ bias, const float* __restrict__ g,
    const float* __restrict__ beta, float* __restrict__ out)
{
    int blk = blockIdx.x;            // w*1024 + l
    int tid = threadIdx.x;
    int w = blk >> 10, l = blk & 1023;
    int b = w >> 2, m = (w >> 1) & 1, n = w & 1;
    int gy = m * 32 + (l >> 5), gx = n * 32 + (l & 31);
    __shared__ float patch[192];
    __shared__ float redA[256], redB[256];
    if (tid < 192) {
        int ic = tid >> 6, k = tid & 63;
        patch[tid] = x[((size_t)(b * 3 + ic) * 512 + gy * 8 + (k >> 3)) * 512 + gx * 8 + (k & 7)];
    }
    __syncthreads();
    float v[3];
#pragma unroll
    for (int r = 0; r < 3; r++) {
        int c = r * 256 + tid;                 // ic == r
        const float4* wp = (const float4*)(wgt + (size_t)c * 64);
        const float* pp = patch + r * 64;
        float acc = bias[c];
#pragma unroll
        for (int k4 = 0; k4 < 16; k4++) {
            float4 wv = wp[k4];
            acc += pp[k4 * 4 + 0] * wv.x + pp[k4 * 4 + 1] * wv.y +
                   pp[k4 * 4 + 2] * wv.z + pp[k4 * 4 + 3] * wv.w;
        }
        v[r] = acc;
    }
    float s = v[0] + v[1] + v[2];
    float sq = v[0] * v[0] + v[1] * v[1] + v[2] * v[2];
    redA[tid] = s; redB[tid] = sq;
    __syncthreads();
    for (int off = 128; off > 0; off >>= 1) {
        if (tid < off) { redA[tid] += redA[tid + off]; redB[tid] += redB[tid + off]; }
        __syncthreads();
    }
    float mu = redA[0] * (1.0f / 768.0f);
    float var = redB[0] * (1.0f / 768.0f) - mu * mu;
    float rstd = rsqrtf(var + 1e-5f);
#pragma unroll
    for (int r = 0; r < 3; r++) {
        int c = r * 256 + tid;
        out[(size_t)blk * 768 + c] = (v[r] - mu) * rstd * g[c] + beta[c];
    }
}

// ---------------- resize conv (16x16 s16, groups=3) + pos_embed + LayerNorm ----------------
__global__ __launch_bounds__(256) void k_conv_resize_ln(
    const float* __restrict__ rx, const float* __restrict__ wgt,
    const float* __restrict__ bias, const float* __restrict__ pe,
    const float* __restrict__ g, const float* __restrict__ beta,
    float* __restrict__ out)
{
    int blk = blockIdx.x;
    int tid = threadIdx.x;
    int w = blk >> 10, l = blk & 1023;
    int b = w >> 2, m = (w >> 1) & 1, n = w & 1;
    int gy = m * 32 + (l >> 5), gx = n * 32 + (l & 31);
    __shared__ float patch[768];
    __shared__ float redA[256], redB[256];
#pragma unroll
    for (int r = 0; r < 3; r++) {
        int pidx = r * 256 + tid;           // ic == r
        int k = pidx & 255;
        patch[pidx] = rx[((size_t)(b * 3 + r) * 1024 + gy * 16 + (k >> 4)) * 1024 + gx * 16 + (k & 15)];
    }
    __syncthreads();
    float v[3];
#pragma unroll
    for (int r = 0; r < 3; r++) {
        int c = r * 256 + tid;
        const float4* wp = (const float4*)(wgt + (size_t)c * 256);
        const float* pp = patch + r * 256;
        float acc = bias[c];
#pragma unroll
        for (int k4 = 0; k4 < 64; k4++) {
            float4 wv = wp[k4];
            acc += pp[k4 * 4 + 0] * wv.x + pp[k4 * 4 + 1] * wv.y +
                   pp[k4 * 4 + 2] * wv.z + pp[k4 * 4 + 3] * wv.w;
        }
        acc += pe[(size_t)c * 4096 + gy * 64 + gx];
        v[r] = acc;
    }
    float s = v[0] + v[1] + v[2];
    float sq = v[0] * v[0] + v[1] * v[1] + v[2] * v[2];
    redA[tid] = s; redB[tid] = sq;
    __syncthreads();
    for (int off = 128; off > 0; off >>= 1) {
        if (tid < off) { redA[tid] += redA[tid + off]; redB[tid] += redB[tid + off]; }
        __syncthreads();
    }
    float mu = redA[0] * (1.0f / 768.0f);
    float var = redB[0] * (1.0f / 768.0f) - mu * mu;
    float rstd = rsqrtf(var + 1e-5f);
#pragma unroll
    for (int r = 0; r < 3; r++) {
        int c = r * 256 + tid;
        out[(size_t)blk * 768 + c] = (v[r] - mu) * rstd * g[c] + beta[c];
    }
}

// ---------------- generic 64x64x16 fp32 tile GEMM: C = A*B^T + bias (all dims %64==0, K%16==0) ----------------
__global__ __launch_bounds__(256) void k_gemm_abt_bias(
    const float* __restrict__ A, const float* __restrict__ B, const float* __restrict__ bias,
    float* __restrict__ C, int K, int lda, int ldb, int ldc)
{
    __shared__ float As[16][68];
    __shared__ float Bs[16][68];
    int tid = threadIdx.x;
    int m0 = blockIdx.y * 64, n0 = blockIdx.x * 64;
    int ar = tid >> 2, ac = (tid & 3) * 4;
    int ty = tid >> 4, tx = tid & 15;
    float acc[4][4] = {};
    for (int k0 = 0; k0 < K; k0 += 16) {
        float4 av = *(const float4*)(A + (size_t)(m0 + ar) * lda + k0 + ac);
        float4 bv = *(const float4*)(B + (size_t)(n0 + ar) * ldb + k0 + ac);
        As[ac + 0][ar] = av.x; As[ac + 1][ar] = av.y; As[ac + 2][ar] = av.z; As[ac + 3][ar] = av.w;
        Bs[ac + 0][ar] = bv.x; Bs[ac + 1][ar] = bv.y; Bs[ac + 2][ar] = bv.z; Bs[ac + 3][ar] = bv.w;
        __syncthreads();
#pragma unroll
        for (int k = 0; k < 16; k++) {
            float4 a4 = *(const float4*)&As[k][ty * 4];
            float4 b4 = *(const float4*)&Bs[k][tx * 4];
            float a[4] = {a4.x, a4.y, a4.z, a4.w};
            float bb2[4] = {b4.x, b4.y, b4.z, b4.w};
#pragma unroll
            for (int r = 0; r < 4; r++)
#pragma unroll
                for (int c = 0; c < 4; c++) acc[r][c] += a[r] * bb2[c];
        }
        __syncthreads();
    }
#pragma unroll
    for (int r = 0; r < 4; r++) {
        int mm = m0 + ty * 4 + r;
#pragma unroll
        for (int c = 0; c < 4; c++) {
            int nn = n0 + tx * 4 + c;
            C[(size_t)mm * ldc + nn] = acc[r][c] + bias[nn];
        }
    }
}

// ---------------- per-(w,h,l) inverse norms: rsqrt(||q96||^2 + 32) ----------------
__global__ __launch_bounds__(256) void k_norm(
    const float* __restrict__ qbuf, const float* __restrict__ bbuf,
    float* __restrict__ qinv, float* __restrict__ binv)
{
    int blk = blockIdx.x;
    int tid = threadIdx.x;
    int which = blk >> 13;
    int row = blk & 8191;                  // w*1024 + l
    const float* src = (which ? bbuf : qbuf) + (size_t)row * 768;
    float* dst = which ? binv : qinv;
    __shared__ float sq[768];
#pragma unroll
    for (int r = 0; r < 3; r++) { int c = r * 256 + tid; float vv = src[c]; sq[c] = vv * vv; }
    __syncthreads();
    if (tid < 8) {
        float s = 32.0f;
        const float* p = sq + tid * 96;
#pragma unroll
        for (int d = 0; d < 96; d++) s += p[d];
        int w = row >> 10, l = row & 1023;
        dst[(size_t)(w * 8 + tid) * 1024 + l] = rsqrtf(s);
    }
}

// ---------------- attn: per (w,h): S = (Q*B^T + R) scaled; M=N=1024, K=96 ----------------
__global__ __launch_bounds__(256) void k_attn(
    const float* __restrict__ qbuf, const float* __restrict__ bbuf,
    const float* __restrict__ qinv, const float* __restrict__ binv,
    const float* __restrict__ rs, float* __restrict__ attn)
{
    int z = blockIdx.z;                    // w*8 + h
    int w = z >> 3, h = z & 7;
    const float* A = qbuf + (size_t)w * 786432 + h * 96;
    const float* B = bbuf + (size_t)w * 786432 + h * 96;
    float* C = attn + (size_t)z * 1048576;
    __shared__ float As[16][68];
    __shared__ float Bs[16][68];
    int tid = threadIdx.x;
    int m0 = blockIdx.y * 64, n0 = blockIdx.x * 64;
    int ar = tid >> 2, ac = (tid & 3) * 4;
    int ty = tid >> 4, tx = tid & 15;
    float acc[4][4] = {};
    for (int k0 = 0; k0 < 96; k0 += 16) {
        float4 av = *(const float4*)(A + (size_t)(m0 + ar) * 768 + k0 + ac);
        float4 bv = *(const float4*)(B + (size_t)(n0 + ar) * 768 + k0 + ac);
        As[ac + 0][ar] = av.x; As[ac + 1][ar] = av.y; As[ac + 2][ar] = av.z; As[ac + 3][ar] = av.w;
        Bs[ac + 0][ar] = bv.x; Bs[ac + 1][ar] = bv.y; Bs[ac + 2][ar] = bv.z; Bs[ac + 3][ar] = bv.w;
        __syncthreads();
#pragma unroll
        for (int k = 0; k < 16; k++) {
            float4 a4 = *(const float4*)&As[k][ty * 4];
            float4 b4 = *(const float4*)&Bs[k][tx * 4];
            float a[4] = {a4.x, a4.y, a4.z, a4.w};
            float bb2[4] = {b4.x, b4.y, b4.z, b4.w};
#pragma unroll
            for (int r = 0; r < 4; r++)
#pragma unroll
                for (int c = 0; c < 4; c++) acc[r][c] += a[r] * bb2[c];
        }
        __syncthreads();
    }
#pragma unroll
    for (int r = 0; r < 4; r++) {
        int i = m0 + ty * 4 + r;
        float qi = qinv[(size_t)z * 1024 + i];
        int iy = i >> 5, ix = i & 31;
#pragma unroll
        for (int c = 0; c < 4; c++) {
            int j = n0 + tx * 4 + c;
            int dy = iy - (j >> 5) + 31;
            int dx = ix - (j & 31) + 31;
            C[(size_t)i * 1024 + j] = (acc[r][c] + rs[dy * 63 + dx]) * qi * binv[(size_t)z * 1024 + j];
        }
    }
}

// ---------------- out: per (w,h): O = S * B ; M=1024, N=96, K=1024; scatter to token layout ----------------
__global__ __launch_bounds__(256) void k_out(
    const float* __restrict__ attn, const float* __restrict__ bbuf,
    float* __restrict__ tok)
{
    int z = blockIdx.z;
    int w = z >> 3, h = z & 7;
    const float* A = attn + (size_t)z * 1048576;           // [i][j], lda 1024
    const float* B = bbuf + (size_t)w * 786432 + h * 96;   // [j][d], ldb 768
    __shared__ float As[16][68];
    __shared__ float Bs[16][68];
    int tid = threadIdx.x;
    int m0 = blockIdx.y * 64, n0 = blockIdx.x * 64;
    int ar = tid >> 2, ac = (tid & 3) * 4;
    int bk = tid >> 4, bn = (tid & 15) * 4;
    int ty = tid >> 4, tx = tid & 15;
    float acc[4][4] = {};
    for (int k0 = 0; k0 < 1024; k0 += 16) {
        float4 av = *(const float4*)(A + (size_t)(m0 + ar) * 1024 + k0 + ac);
        As[ac + 0][ar] = av.x; As[ac + 1][ar] = av.y; As[ac + 2][ar] = av.z; As[ac + 3][ar] = av.w;
        int col = n0 + bn;
        float4 bv = make_float4(0.f, 0.f, 0.f, 0.f);
        if (col < 96) bv = *(const float4*)(B + (size_t)(k0 + bk) * 768 + col);
        Bs[bk][bn + 0] = bv.x; Bs[bk][bn + 1] = bv.y; Bs[bk][bn + 2] = bv.z; Bs[bk][bn + 3] = bv.w;
        __syncthreads();
#pragma unroll
        for (int k = 0; k < 16; k++) {
            float4 a4 = *(const float4*)&As[k][ty * 4];
            float4 b4 = *(const float4*)&Bs[k][tx * 4];
            float a[4] = {a4.x, a4.y, a4.z, a4.w};
            float bb2[4] = {b4.x, b4.y, b4.z, b4.w};
#pragma unroll
            for (int r = 0; r < 4; r++)
#pragma unroll
                for (int c = 0; c < 4; c++) acc[r][c] += a[r] * bb2[c];
        }
        __syncthreads();
    }
    int b = w >> 2, wm = (w >> 1) & 1, wn = w & 1;
#pragma unroll
    for (int r = 0; r < 4; r++) {
        int i = m0 + ty * 4 + r;
        int t = (b * 64 + wm * 32 + (i >> 5)) * 64 + wn * 32 + (i & 31);
#pragma unroll
        for (int c = 0; c < 4; c++) {
            int d = n0 + tx * 4 + c;
            if (d < 96) tok[(size_t)t * 768 + h * 96 + d] = acc[r][c];
        }
    }
}

// ---------------- final proj: C = tok * projw^T + projb, scatter to (B,768,64,64) ----------------
__global__ __launch_bounds__(256) void k_proj(
    const float* __restrict__ tok, const float* __restrict__ pw,
    const float* __restrict__ pb, float* __restrict__ out0)
{
    __shared__ float As[16][68];
    __shared__ float Bs[16][68];
    int tid = threadIdx.x;
    int m0 = blockIdx.y * 64, n0 = blockIdx.x * 64;
    int ar = tid >> 2, ac = (tid & 3) * 4;
    int ty = tid >> 4, tx = tid & 15;
    float acc[4][4] = {};
    for (int k0 = 0; k0 < 768; k0 += 16) {
        float4 av = *(const float4*)(tok + (size_t)(m0 + ar) * 768 + k0 + ac);
        float4 bv = *(const float4*)(pw + (size_t)(n0 + ar) * 768 + k0 + ac);
        As[ac + 0][ar] = av.x; As[ac + 1][ar] = av.y; As[ac + 2][ar] = av.z; As[ac + 3][ar] = av.w;
        Bs[ac + 0][ar] = bv.x; Bs[ac + 1][ar] = bv.y; Bs[ac + 2][ar] = bv.z; Bs[ac + 3][ar] = bv.w;
        __syncthreads();
#pragma unroll
        for (int k = 0; k < 16; k++) {
            float4 a4 = *(const float4*)&As[k][ty * 4];
            float4 b4 = *(const float4*)&Bs[k][tx * 4];
            float a[4] = {a4.x, a4.y, a4.z, a4.w};
            float bb2[4] = {b4.x, b4.y, b4.z, b4.w};
#pragma unroll
            for (int r = 0; r < 4; r++)
#pragma unroll
                for (int c = 0; c < 4; c++) acc[r][c] += a[r] * bb2[c];
        }
        __syncthreads();
    }
#pragma unroll
    for (int r = 0; r < 4; r++) {
        int t = m0 + ty * 4 + r;
        int b = t >> 12, p = t & 4095;
#pragma unroll
        for (int c = 0; c < 4; c++) {
            int cc = n0 + tx * 4 + c;
            out0[(size_t)b * 3145728 + (size_t)cc * 4096 + p] = acc[r][c] + pb[cc];
        }
    }
}

extern "C" void kernel_launch(void* const* d_in, const int* in_sizes, int n_in,
                              void* d_out, int out_size, void* d_ws, size_t ws_size,
                              hipStream_t stream)
{
    const float* x   = (const float*)d_in[0];
    const float* ow  = (const float*)d_in[1];
    const float* ob  = (const float*)d_in[2];
    const float* rw  = (const float*)d_in[3];
    const float* rb  = (const float*)d_in[4];
    const float* pe  = (const float*)d_in[5];
    const float* nbg = (const float*)d_in[6];
    const float* nbb = (const float*)d_in[7];
    const float* nqg = (const float*)d_in[8];
    const float* nqb = (const float*)d_in[9];
    const float* qw  = (const float*)d_in[10];
    const float* qb  = (const float*)d_in[11];
    const float* bw  = (const float*)d_in[12];
    const float* bb  = (const float*)d_in[13];
    const float* pw  = (const float*)d_in[14];
    const float* pb  = (const float*)d_in[15];

    float* out0 = (float*)d_out;                 // (2,768,64,64) = 6291456
    float* attn = out0 + 6291456;                // (8,8,1024,1024) = 67108864

    float* ws   = (float*)d_ws;
    float* rx   = ws;                            // 6291456
    float* opb  = ws + 1 * 6291456;              // op, LayerNormed, [w*1024+l][768]
    float* rpb  = ws + 2 * 6291456;              // rp, LayerNormed
    float* qbuf = ws + 3 * 6291456;              // q projection
    float* bbuf = ws + 4 * 6291456;              // b projection (= tmp_b)
    float* qinv = ws + 5 * 6291456;              // 65536
    float* binv = qinv + 65536;                  // 65536
    float* rs   = binv + 65536;                  // 3969
    float* tok  = rx;                            // reuse rx (dead after resize conv)

    k_resize<<<24576, 256, 0, stream>>>(x, rx);
    k_rsmall<<<16, 256, 0, stream>>>(rs);
    k_conv_origin_ln<<<8192, 256, 0, stream>>>(x, ow, ob, nbg, nbb, opb);
    k_conv_resize_ln<<<8192, 256, 0, stream>>>(rx, rw, rb, pe, nqg, nqb, rpb);

    dim3 g1(12, 128);   // N=768/64, M=8192/64
    k_gemm_abt_bias<<<g1, 256, 0, stream>>>(rpb, qw, qb, qbuf, 768, 768, 768, 768);
    k_gemm_abt_bias<<<g1, 256, 0, stream>>>(opb, bw, bb, bbuf, 768, 768, 768, 768);

    k_norm<<<16384, 256, 0, stream>>>(qbuf, bbuf, qinv, binv);

    dim3 ga(16, 16, 64);
    k_attn<<<ga, 256, 0, stream>>>(qbuf, bbuf, qinv, binv, rs, attn);

    dim3 go(2, 16, 64);
    k_out<<<go, 256, 0, stream>>>(attn, bbuf, tok);

    k_proj<<<g1, 256, 0, stream>>>(tok, pw, pb, out0);
}

// Round 2
// 1292.308 us; speedup vs baseline: 2.0446x; 2.0446x over previous
//
#include <hip/hip_runtime.h>
#include <hip/hip_bf16.h>
#include <math.h>

// ---------- problem constants ----------
// x (2,3,512,512); grid 64x64 tokens of 768 ch; 8 windows of 32x32=1024 tokens
// heads=8, HD=96, F=16, rope feat dim 64, ||feat||^2 = 32 exactly.

// ---------------- bilinear 2x resize (clamp-to-edge == jax renormalized) ----------------
__global__ __launch_bounds__(256) void k_resize(const float* __restrict__ x, float* __restrict__ rx)
{
    int idx = blockIdx.x * 256 + threadIdx.x;           // < 6291456 exactly
    int X = idx & 1023;
    int Y = (idx >> 10) & 1023;
    int bc = idx >> 20;                                 // 0..5 (b*3+c)
    float sy = Y * 0.5f - 0.25f;
    float sx = X * 0.5f - 0.25f;
    int y0 = (int)floorf(sy), x0 = (int)floorf(sx);
    float fy = sy - (float)y0, fx = sx - (float)x0;
    int y1 = y0 + 1, x1 = x0 + 1;
    y0 = max(0, min(511, y0)); y1 = max(0, min(511, y1));
    x0 = max(0, min(511, x0)); x1 = max(0, min(511, x1));
    const float* p = x + (size_t)bc * (512 * 512);
    float v00 = p[y0 * 512 + x0], v01 = p[y0 * 512 + x1];
    float v10 = p[y1 * 512 + x0], v11 = p[y1 * 512 + x1];
    rx[idx] = (1.f - fy) * ((1.f - fx) * v00 + fx * v01) + fy * ((1.f - fx) * v10 + fx * v11);
}

// ---------------- rope relative table R[dy+31][dx+31] ----------------
__global__ void k_rsmall(float* __restrict__ rs)
{
    int e = blockIdx.x * 256 + threadIdx.x;
    if (e >= 63 * 63) return;
    float dy = (float)(e / 63 - 31);
    float dx = (float)(e % 63 - 31);
    float s = 0.f;
    for (int f = 0; f < 16; f++) {
        float invf = powf(10.0f, -(float)f / 16.0f);
        s += cosf(dx * invf) + cosf(dy * invf);
    }
    rs[e] = s;
}

// ---------------- resize conv as tile GEMM: tokens(8192) x K(256) x ch(768, 3 groups) ----------------
// out_pre[token][c] = conv + bias + pos_embed   (LN in separate pass)
__global__ __launch_bounds__(256) void k_convr(
    const float* __restrict__ rx, const float* __restrict__ wgt,
    const float* __restrict__ bias, const float* __restrict__ pe,
    float* __restrict__ out)
{
    __shared__ float As[16][68];
    __shared__ float Bs[16][68];
    int tid = threadIdx.x;
    int m0 = blockIdx.y * 64;         // token tile
    int cbase = blockIdx.x * 64;      // channel tile (stays within one group: 256%64==0)
    int ic = cbase >> 8;              // input channel for this group
    int ar = tid >> 2, ac = (tid & 3) * 4;
    int ty = tid >> 4, tx = tid & 15;

    // A-load row token coords
    int mtok = m0 + ar;
    int w = mtok >> 10, l = mtok & 1023;
    int b = w >> 2, wm = (w >> 1) & 1, wn = w & 1;
    int gy = wm * 32 + (l >> 5), gx = wn * 32 + (l & 31);
    const float* abase = rx + ((size_t)(b * 3 + ic) * 1024 + gy * 16) * 1024 + gx * 16;
    const float* bbase = wgt + (size_t)(cbase + ar) * 256;

    float acc[4][4] = {};
    for (int k0 = 0; k0 < 256; k0 += 16) {
        // k = k0+ac; patch row = k>>4 = k0>>4 (k0 mult of 16, ac<16), col = ac
        float4 av = *(const float4*)(abase + (size_t)(k0 >> 4) * 1024 + ac);
        float4 bv = *(const float4*)(bbase + k0 + ac);
        As[ac + 0][ar] = av.x; As[ac + 1][ar] = av.y; As[ac + 2][ar] = av.z; As[ac + 3][ar] = av.w;
        Bs[ac + 0][ar] = bv.x; Bs[ac + 1][ar] = bv.y; Bs[ac + 2][ar] = bv.z; Bs[ac + 3][ar] = bv.w;
        __syncthreads();
#pragma unroll
        for (int k = 0; k < 16; k++) {
            float4 a4 = *(const float4*)&As[k][ty * 4];
            float4 b4 = *(const float4*)&Bs[k][tx * 4];
            float a[4] = {a4.x, a4.y, a4.z, a4.w};
            float bb2[4] = {b4.x, b4.y, b4.z, b4.w};
#pragma unroll
            for (int r = 0; r < 4; r++)
#pragma unroll
                for (int c = 0; c < 4; c++) acc[r][c] += a[r] * bb2[c];
        }
        __syncthreads();
    }
#pragma unroll
    for (int r = 0; r < 4; r++) {
        int t = m0 + ty * 4 + r;
        int tw = t >> 10, tl = t & 1023;
        int tgy = ((tw >> 1) & 1) * 32 + (tl >> 5);
        int tgx = (tw & 1) * 32 + (tl & 31);
#pragma unroll
        for (int c = 0; c < 4; c++) {
            int cc = cbase + tx * 4 + c;
            out[(size_t)t * 768 + cc] = acc[r][c] + bias[cc] + pe[(size_t)cc * 4096 + tgy * 64 + tgx];
        }
    }
}

// ---------------- origin conv as tile GEMM: tokens(8192) x K(64) x ch(768, 3 groups) ----------------
__global__ __launch_bounds__(256) void k_convo(
    const float* __restrict__ x, const float* __restrict__ wgt,
    const float* __restrict__ bias, float* __restrict__ out)
{
    __shared__ float As[16][68];
    __shared__ float Bs[16][68];
    int tid = threadIdx.x;
    int m0 = blockIdx.y * 64;
    int cbase = blockIdx.x * 64;
    int ic = cbase >> 8;
    int ar = tid >> 2, ac = (tid & 3) * 4;
    int ty = tid >> 4, tx = tid & 15;

    int mtok = m0 + ar;
    int w = mtok >> 10, l = mtok & 1023;
    int b = w >> 2, wm = (w >> 1) & 1, wn = w & 1;
    int gy = wm * 32 + (l >> 5), gx = wn * 32 + (l & 31);
    const float* abase = x + ((size_t)(b * 3 + ic) * 512 + gy * 8) * 512 + gx * 8;
    const float* bbase = wgt + (size_t)(cbase + ar) * 64;

    float acc[4][4] = {};
    for (int k0 = 0; k0 < 64; k0 += 16) {
        int k = k0 + ac;                 // patch row = k>>3, col = k&7 (float4-aligned)
        float4 av = *(const float4*)(abase + (size_t)(k >> 3) * 512 + (k & 7));
        float4 bv = *(const float4*)(bbase + k);
        As[ac + 0][ar] = av.x; As[ac + 1][ar] = av.y; As[ac + 2][ar] = av.z; As[ac + 3][ar] = av.w;
        Bs[ac + 0][ar] = bv.x; Bs[ac + 1][ar] = bv.y; Bs[ac + 2][ar] = bv.z; Bs[ac + 3][ar] = bv.w;
        __syncthreads();
#pragma unroll
        for (int k2 = 0; k2 < 16; k2++) {
            float4 a4 = *(const float4*)&As[k2][ty * 4];
            float4 b4 = *(const float4*)&Bs[k2][tx * 4];
            float a[4] = {a4.x, a4.y, a4.z, a4.w};
            float bb2[4] = {b4.x, b4.y, b4.z, b4.w};
#pragma unroll
            for (int r = 0; r < 4; r++)
#pragma unroll
                for (int c = 0; c < 4; c++) acc[r][c] += a[r] * bb2[c];
        }
        __syncthreads();
    }
#pragma unroll
    for (int r = 0; r < 4; r++) {
        int t = m0 + ty * 4 + r;
#pragma unroll
        for (int c = 0; c < 4; c++) {
            int cc = cbase + tx * 4 + c;
            out[(size_t)t * 768 + cc] = acc[r][c] + bias[cc];
        }
    }
}

// ---------------- LayerNorm pass: one block per token ----------------
__global__ __launch_bounds__(256) void k_ln(
    const float* __restrict__ in, const float* __restrict__ g,
    const float* __restrict__ beta, float* __restrict__ out)
{
    int blk = blockIdx.x;
    int tid = threadIdx.x;
    __shared__ float redA[256], redB[256];
    float v[3];
#pragma unroll
    for (int r = 0; r < 3; r++) v[r] = in[(size_t)blk * 768 + r * 256 + tid];
    float s = v[0] + v[1] + v[2];
    float sq = v[0] * v[0] + v[1] * v[1] + v[2] * v[2];
    redA[tid] = s; redB[tid] = sq;
    __syncthreads();
    for (int off = 128; off > 0; off >>= 1) {
        if (tid < off) { redA[tid] += redA[tid + off]; redB[tid] += redB[tid + off]; }
        __syncthreads();
    }
    float mu = redA[0] * (1.0f / 768.0f);
    float var = redB[0] * (1.0f / 768.0f) - mu * mu;
    float rstd = rsqrtf(var + 1e-5f);
#pragma unroll
    for (int r = 0; r < 3; r++) {
        int c = r * 256 + tid;
        out[(size_t)blk * 768 + c] = (v[r] - mu) * rstd * g[c] + beta[c];
    }
}

// ---------------- generic 64x64x16 fp32 tile GEMM: C = A*B^T + bias ----------------
__global__ __launch_bounds__(256) void k_gemm_abt_bias(
    const float* __restrict__ A, const float* __restrict__ B, const float* __restrict__ bias,
    float* __restrict__ C, int K, int lda, int ldb, int ldc)
{
    __shared__ float As[16][68];
    __shared__ float Bs[16][68];
    int tid = threadIdx.x;
    int m0 = blockIdx.y * 64, n0 = blockIdx.x * 64;
    int ar = tid >> 2, ac = (tid & 3) * 4;
    int ty = tid >> 4, tx = tid & 15;
    float acc[4][4] = {};
    for (int k0 = 0; k0 < K; k0 += 16) {
        float4 av = *(const float4*)(A + (size_t)(m0 + ar) * lda + k0 + ac);
        float4 bv = *(const float4*)(B + (size_t)(n0 + ar) * ldb + k0 + ac);
        As[ac + 0][ar] = av.x; As[ac + 1][ar] = av.y; As[ac + 2][ar] = av.z; As[ac + 3][ar] = av.w;
        Bs[ac + 0][ar] = bv.x; Bs[ac + 1][ar] = bv.y; Bs[ac + 2][ar] = bv.z; Bs[ac + 3][ar] = bv.w;
        __syncthreads();
#pragma unroll
        for (int k = 0; k < 16; k++) {
            float4 a4 = *(const float4*)&As[k][ty * 4];
            float4 b4 = *(const float4*)&Bs[k][tx * 4];
            float a[4] = {a4.x, a4.y, a4.z, a4.w};
            float bb2[4] = {b4.x, b4.y, b4.z, b4.w};
#pragma unroll
            for (int r = 0; r < 4; r++)
#pragma unroll
                for (int c = 0; c < 4; c++) acc[r][c] += a[r] * bb2[c];
        }
        __syncthreads();
    }
#pragma unroll
    for (int r = 0; r < 4; r++) {
        int mm = m0 + ty * 4 + r;
#pragma unroll
        for (int c = 0; c < 4; c++) {
            int nn = n0 + tx * 4 + c;
            C[(size_t)mm * ldc + nn] = acc[r][c] + bias[nn];
        }
    }
}

// ---------------- per-(w,h,l) inverse norms: rsqrt(||q96||^2 + 32) ----------------
__global__ __launch_bounds__(256) void k_norm(
    const float* __restrict__ qbuf, const float* __restrict__ bbuf,
    float* __restrict__ qinv, float* __restrict__ binv)
{
    int blk = blockIdx.x;
    int tid = threadIdx.x;
    int which = blk >> 13;
    int row = blk & 8191;                  // w*1024 + l
    const float* src = (which ? bbuf : qbuf) + (size_t)row * 768;
    float* dst = which ? binv : qinv;
    __shared__ float sq[768];
#pragma unroll
    for (int r = 0; r < 3; r++) { int c = r * 256 + tid; float vv = src[c]; sq[c] = vv * vv; }
    __syncthreads();
    if (tid < 8) {
        float s = 32.0f;
        const float* p = sq + tid * 96;
#pragma unroll
        for (int d = 0; d < 96; d++) s += p[d];
        int w = row >> 10, l = row & 1023;
        dst[(size_t)(w * 8 + tid) * 1024 + l] = rsqrtf(s);
    }
}

// ---------------- attn: per (w,h): S = (Q*B^T + R) scaled; M=N=1024, K=96 ----------------
__global__ __launch_bounds__(256) void k_attn(
    const float* __restrict__ qbuf, const float* __restrict__ bbuf,
    const float* __restrict__ qinv, const float* __restrict__ binv,
    const float* __restrict__ rs, float* __restrict__ attn)
{
    int z = blockIdx.z;                    // w*8 + h
    int w = z >> 3, h = z & 7;
    const float* A = qbuf + (size_t)w * 786432 + h * 96;
    const float* B = bbuf + (size_t)w * 786432 + h * 96;
    float* C = attn + (size_t)z * 1048576;
    __shared__ float As[16][68];
    __shared__ float Bs[16][68];
    int tid = threadIdx.x;
    int m0 = blockIdx.y * 64, n0 = blockIdx.x * 64;
    int ar = tid >> 2, ac = (tid & 3) * 4;
    int ty = tid >> 4, tx = tid & 15;
    float acc[4][4] = {};
    for (int k0 = 0; k0 < 96; k0 += 16) {
        float4 av = *(const float4*)(A + (size_t)(m0 + ar) * 768 + k0 + ac);
        float4 bv = *(const float4*)(B + (size_t)(n0 + ar) * 768 + k0 + ac);
        As[ac + 0][ar] = av.x; As[ac + 1][ar] = av.y; As[ac + 2][ar] = av.z; As[ac + 3][ar] = av.w;
        Bs[ac + 0][ar] = bv.x; Bs[ac + 1][ar] = bv.y; Bs[ac + 2][ar] = bv.z; Bs[ac + 3][ar] = bv.w;
        __syncthreads();
#pragma unroll
        for (int k = 0; k < 16; k++) {
            float4 a4 = *(const float4*)&As[k][ty * 4];
            float4 b4 = *(const float4*)&Bs[k][tx * 4];
            float a[4] = {a4.x, a4.y, a4.z, a4.w};
            float bb2[4] = {b4.x, b4.y, b4.z, b4.w};
#pragma unroll
            for (int r = 0; r < 4; r++)
#pragma unroll
                for (int c = 0; c < 4; c++) acc[r][c] += a[r] * bb2[c];
        }
        __syncthreads();
    }
#pragma unroll
    for (int r = 0; r < 4; r++) {
        int i = m0 + ty * 4 + r;
        float qi = qinv[(size_t)z * 1024 + i];
        int iy = i >> 5, ix = i & 31;
#pragma unroll
        for (int c = 0; c < 4; c++) {
            int j = n0 + tx * 4 + c;
            int dy = iy - (j >> 5) + 31;
            int dx = ix - (j & 31) + 31;
            C[(size_t)i * 1024 + j] = (acc[r][c] + rs[dy * 63 + dx]) * qi * binv[(size_t)z * 1024 + j];
        }
    }
}

// ---------------- out: per (w,h): O = S * B ; M=1024, N=96, K=1024; scatter to token layout ----------------
__global__ __launch_bounds__(256) void k_out(
    const float* __restrict__ attn, const float* __restrict__ bbuf,
    float* __restrict__ tok)
{
    int z = blockIdx.z;
    int w = z >> 3, h = z & 7;
    const float* A = attn + (size_t)z * 1048576;           // [i][j], lda 1024
    const float* B = bbuf + (size_t)w * 786432 + h * 96;   // [j][d], ldb 768
    __shared__ float As[16][68];
    __shared__ float Bs[16][68];
    int tid = threadIdx.x;
    int m0 = blockIdx.y * 64, n0 = blockIdx.x * 64;
    int ar = tid >> 2, ac = (tid & 3) * 4;
    int bk = tid >> 4, bn = (tid & 15) * 4;
    int ty = tid >> 4, tx = tid & 15;
    float acc[4][4] = {};
    for (int k0 = 0; k0 < 1024; k0 += 16) {
        float4 av = *(const float4*)(A + (size_t)(m0 + ar) * 1024 + k0 + ac);
        As[ac + 0][ar] = av.x; As[ac + 1][ar] = av.y; As[ac + 2][ar] = av.z; As[ac + 3][ar] = av.w;
        int col = n0 + bn;
        float4 bv = make_float4(0.f, 0.f, 0.f, 0.f);
        if (col < 96) bv = *(const float4*)(B + (size_t)(k0 + bk) * 768 + col);
        Bs[bk][bn + 0] = bv.x; Bs[bk][bn + 1] = bv.y; Bs[bk][bn + 2] = bv.z; Bs[bk][bn + 3] = bv.w;
        __syncthreads();
#pragma unroll
        for (int k = 0; k < 16; k++) {
            float4 a4 = *(const float4*)&As[k][ty * 4];
            float4 b4 = *(const float4*)&Bs[k][tx * 4];
            float a[4] = {a4.x, a4.y, a4.z, a4.w};
            float bb2[4] = {b4.x, b4.y, b4.z, b4.w};
#pragma unroll
            for (int r = 0; r < 4; r++)
#pragma unroll
                for (int c = 0; c < 4; c++) acc[r][c] += a[r] * bb2[c];
        }
        __syncthreads();
    }
    int b = w >> 2, wm = (w >> 1) & 1, wn = w & 1;
#pragma unroll
    for (int r = 0; r < 4; r++) {
        int i = m0 + ty * 4 + r;
        int t = (b * 64 + wm * 32 + (i >> 5)) * 64 + wn * 32 + (i & 31);
#pragma unroll
        for (int c = 0; c < 4; c++) {
            int d = n0 + tx * 4 + c;
            if (d < 96) tok[(size_t)t * 768 + h * 96 + d] = acc[r][c];
        }
    }
}

// ---------------- final proj: C = tok * projw^T + projb, scatter to (B,768,64,64) ----------------
__global__ __launch_bounds__(256) void k_proj(
    const float* __restrict__ tok, const float* __restrict__ pw,
    const float* __restrict__ pb, float* __restrict__ out0)
{
    __shared__ float As[16][68];
    __shared__ float Bs[16][68];
    int tid = threadIdx.x;
    int m0 = blockIdx.y * 64, n0 = blockIdx.x * 64;
    int ar = tid >> 2, ac = (tid & 3) * 4;
    int ty = tid >> 4, tx = tid & 15;
    float acc[4][4] = {};
    for (int k0 = 0; k0 < 768; k0 += 16) {
        float4 av = *(const float4*)(tok + (size_t)(m0 + ar) * 768 + k0 + ac);
        float4 bv = *(const float4*)(pw + (size_t)(n0 + ar) * 768 + k0 + ac);
        As[ac + 0][ar] = av.x; As[ac + 1][ar] = av.y; As[ac + 2][ar] = av.z; As[ac + 3][ar] = av.w;
        Bs[ac + 0][ar] = bv.x; Bs[ac + 1][ar] = bv.y; Bs[ac + 2][ar] = bv.z; Bs[ac + 3][ar] = bv.w;
        __syncthreads();
#pragma unroll
        for (int k = 0; k < 16; k++) {
            float4 a4 = *(const float4*)&As[k][ty * 4];
            float4 b4 = *(const float4*)&Bs[k][tx * 4];
            float a[4] = {a4.x, a4.y, a4.z, a4.w};
            float bb2[4] = {b4.x, b4.y, b4.z, b4.w};
#pragma unroll
            for (int r = 0; r < 4; r++)
#pragma unroll
                for (int c = 0; c < 4; c++) acc[r][c] += a[r] * bb2[c];
        }
        __syncthreads();
    }
#pragma unroll
    for (int r = 0; r < 4; r++) {
        int t = m0 + ty * 4 + r;
        int b = t >> 12, p = t & 4095;
#pragma unroll
        for (int c = 0; c < 4; c++) {
            int cc = n0 + tx * 4 + c;
            out0[(size_t)b * 3145728 + (size_t)cc * 4096 + p] = acc[r][c] + pb[cc];
        }
    }
}

extern "C" void kernel_launch(void* const* d_in, const int* in_sizes, int n_in,
                              void* d_out, int out_size, void* d_ws, size_t ws_size,
                              hipStream_t stream)
{
    const float* x   = (const float*)d_in[0];
    const float* ow  = (const float*)d_in[1];
    const float* ob  = (const float*)d_in[2];
    const float* rw  = (const float*)d_in[3];
    const float* rb  = (const float*)d_in[4];
    const float* pe  = (const float*)d_in[5];
    const float* nbg = (const float*)d_in[6];
    const float* nbb = (const float*)d_in[7];
    const float* nqg = (const float*)d_in[8];
    const float* nqb = (const float*)d_in[9];
    const float* qw  = (const float*)d_in[10];
    const float* qb  = (const float*)d_in[11];
    const float* bw  = (const float*)d_in[12];
    const float* bb  = (const float*)d_in[13];
    const float* pw  = (const float*)d_in[14];
    const float* pb  = (const float*)d_in[15];

    float* out0 = (float*)d_out;                 // (2,768,64,64) = 6291456
    float* attn = out0 + 6291456;                // (8,8,1024,1024) = 67108864

    float* ws   = (float*)d_ws;
    float* rx   = ws;                            // 6291456
    float* opb  = ws + 1 * 6291456;              // op, LayerNormed, [w*1024+l][768]
    float* rpb  = ws + 2 * 6291456;              // rp, LayerNormed
    float* qbuf = ws + 3 * 6291456;              // q projection (aliases rpre before q GEMM)
    float* bbuf = ws + 4 * 6291456;              // b projection (aliases opre before b GEMM)
    float* qinv = ws + 5 * 6291456;              // 65536
    float* binv = qinv + 65536;                  // 65536
    float* rs   = binv + 65536;                  // 3969
    float* tok  = rx;                            // reuse rx (dead after resize conv)
    float* rpre = qbuf;                          // pre-LN resize conv out (dead after LN)
    float* opre = bbuf;                          // pre-LN origin conv out (dead after LN)

    k_resize<<<24576, 256, 0, stream>>>(x, rx);
    k_rsmall<<<16, 256, 0, stream>>>(rs);

    dim3 gc(12, 128);   // 768/64 channels, 8192/64 tokens
    k_convr<<<gc, 256, 0, stream>>>(rx, rw, rb, pe, rpre);
    k_convo<<<gc, 256, 0, stream>>>(x, ow, ob, opre);
    k_ln<<<8192, 256, 0, stream>>>(rpre, nqg, nqb, rpb);
    k_ln<<<8192, 256, 0, stream>>>(opre, nbg, nbb, opb);

    dim3 g1(12, 128);   // N=768/64, M=8192/64
    k_gemm_abt_bias<<<g1, 256, 0, stream>>>(rpb, qw, qb, qbuf, 768, 768, 768, 768);
    k_gemm_abt_bias<<<g1, 256, 0, stream>>>(opb, bw, bb, bbuf, 768, 768, 768, 768);

    k_norm<<<16384, 256, 0, stream>>>(qbuf, bbuf, qinv, binv);

    dim3 ga(16, 16, 64);
    k_attn<<<ga, 256, 0, stream>>>(qbuf, bbuf, qinv, binv, rs, attn);

    dim3 go(2, 16, 64);
    k_out<<<go, 256, 0, stream>>>(attn, bbuf, tok);

    k_proj<<<g1, 256, 0, stream>>>(tok, pw, pb, out0);
}